// Round 13
// baseline (24.574 us; speedup 1.0000x reference)
//
#include <hip/hip_runtime.h>

#define NEG_SLOPE 0.01f

typedef _Float16 f16;
typedef _Float16 f16x4 __attribute__((ext_vector_type(4)));
typedef float    f32x4 __attribute__((ext_vector_type(4)));

__device__ __forceinline__ float leaky(float v) {
    return fmaxf(v, NEG_SLOPE * v);
}

// ------------- Fully fused, 512-thr blocks, row-pair + j-half per wave -------------
// 1024 blocks x 512 thr (8 waves). Block covers rows blockIdx*8 .. +7 (same b),
// as 4 row-pairs. Wave wv: pair = wv&3 (rows ia=2*pair, ia+1), half = wv>>2
// (j-subtiles [half*16, half*16+16)). Sharing as R11 (pj ds_read + weights
// serve both rows), but per-wave serial work is HALVED and waves/SIMD = 8.
// Phase 1 split: half-0 wave does the pair's node MLP; half-1 wave does the
// pair's sigmoid rows (+vS). One barrier covers pjbuf+sigbuf.
// Phase 2: 16 subtiles, prefetch-pipelined, sig-premultiplied leaky:
//   acc[e] += (0.505sig)*d1[e] + (0.495sig)*|d1[e]|
// Epilogue: pp = acc.w3 (+ node | + bc3*vS); butterfly; cross-wave pair sum.
__global__ __launch_bounds__(512, 8) void fused_split(
    const float* __restrict__ x,
    const float* __restrict__ Wn1, const float* __restrict__ bn1,
    const float* __restrict__ Wn2, const float* __restrict__ bn2,
    const float* __restrict__ Wn3, const float* __restrict__ bn3,
    const float* __restrict__ Wc1, const float* __restrict__ bc1,
    const float* __restrict__ Wc2, const float* __restrict__ bc2,
    const float* __restrict__ Wc3, const float* __restrict__ bc3,
    const float* __restrict__ A_param,
    float* __restrict__ out)
{
    __shared__ unsigned char pjbuf[512 * 32];   // f16 [512][16], swizzled
    __shared__ float2 shn[4][64];               // node h1 pairs, per row-pair
    __shared__ float2 sigbuf[4][512];           // sigmoid pairs, per row-pair
    __shared__ float2 sred[8];                  // per-wave partial (ppa, ppb)

    const int t    = threadIdx.x;
    const int l    = t & 63;
    const int wv   = t >> 6;          // 0..7
    const int pair = wv & 3;          // row-pair within block
    const int half = wv >> 2;         // j-half
    const int p    = l & 15;          // pair slot within 16-j tile
    const int g    = l >> 4;          // channel group
    const int c4   = g << 2;
    const int ia = blockIdx.x * 8 + pair * 2;   // even global row (b*512 + i0)
    const int ib = ia + 1;
    const int bb = ia >> 9;
    const int i0 = ia & 511, i1 = i0 + 1;

    const float* xb = x + bb * 1024;  // x[b][j][2]

    // ---- Phase 1a: stage pj (f16) into LDS; thread t covers j = t ----
    {
        const int j = t;
        const float2 xj = *reinterpret_cast<const float2*>(xb + j * 2);
        f16 v[16];
        #pragma unroll
        for (int c = 0; c < 16; ++c)
            v[c] = (f16)fmaf(xj.x, Wc1[c], xj.y * Wc1[16 + c]);
        const int sw = ((j >> 2) & 3) << 3;
        #pragma unroll
        for (int gg = 0; gg < 4; ++gg) {
            const int addr = j * 32 + ((gg << 3) ^ sw);
            *reinterpret_cast<f16x4*>(pjbuf + addr) =
                (f16x4){v[4*gg], v[4*gg+1], v[4*gg+2], v[4*gg+3]};
        }
    }

    const float2 xia = *reinterpret_cast<const float2*>(xb + i0 * 2);
    const float2 xib = *reinterpret_cast<const float2*>(xb + i1 * 2);

    // ---- Phase 1b: weight fragments (row-independent) + per-row piu ----
    f16x4 w2lo, w2hi, piua, piub;
    f32x4 c1;
    float w3r[4];
    #pragma unroll
    for (int e = 0; e < 4; ++e) {
        const int c = c4 + e;
        const float w2 = Wc2[c * 16 + p];
        const f16 hw = (f16)w2;
        w2hi[e] = hw; w2lo[e] = (f16)(w2 - (float)hw);
        c1[e]  = bc2[c];
        w3r[e] = Wc3[c];
        const float wi0 = Wc1[32 + c], wi1 = Wc1[48 + c], bce = bc1[c];
        piua[e] = (f16)fmaf(xia.x, wi0, fmaf(xia.y, wi1, bce));
        piub[e] = (f16)fmaf(xib.x, wi0, fmaf(xib.y, wi1, bce));
    }
    const f16x4 slope4 = {(f16)NEG_SLOPE, (f16)NEG_SLOPE, (f16)NEG_SLOPE, (f16)NEG_SLOPE};

    // ---- Phase 1c/1d: split per half ----
    float pna = 0.f, pnb = 0.f;       // node partials (half 0)
    float vsa = 0.f, vsb = 0.f;       // sigmoid sums (half 1)
    if (half == 0) {
        // node MLP for both rows (shared Wn2 loads, intra-wave LDS)
        const float h1a = leaky(fmaf(xia.x, Wn1[l], fmaf(xia.y, Wn1[64 + l], bn1[l])));
        const float h1b = leaky(fmaf(xib.x, Wn1[l], fmaf(xib.y, Wn1[64 + l], bn1[l])));
        shn[pair][l] = make_float2(h1a, h1b);
        float na0 = bn2[l], nb0 = 0.f, na1 = 0.f, nb1 = 0.f;
        #pragma unroll 8
        for (int c = 0; c < 64; c += 2) {
            const float w0 = Wn2[c * 64 + l];
            const float w1 = Wn2[(c + 1) * 64 + l];
            const float2 h0 = shn[pair][c];
            const float2 h2 = shn[pair][c + 1];
            na0 = fmaf(h0.x, w0, na0);
            nb0 = fmaf(h0.y, w0, nb0);
            na1 = fmaf(h2.x, w1, na1);
            nb1 = fmaf(h2.y, w1, nb1);
        }
        pna = leaky(na0 + na1) * Wn3[l];
        pnb = leaky(nb0 + nb1 + bn2[l]) * Wn3[l];
    } else {
        // sigmoid rows for both i's -> LDS
        const float* Ara = A_param + i0 * 512;
        const float* Arb = Ara + 512;
        #pragma unroll
        for (int s = 0; s < 8; ++s) {
            const int j = s * 64 + l;
            float sa = __fdividef(1.f, 1.f + __expf(-Ara[j]));
            float sb = __fdividef(1.f, 1.f + __expf(-Arb[j]));
            if (j == i0) sa = 0.f;    // sigmoid(0 - 1e5) == 0 in f32
            if (j == i1) sb = 0.f;
            vsa += sa; vsb += sb;
            sigbuf[pair][j] = make_float2(sa, sb);
        }
    }

    __syncthreads();   // pjbuf + sigbuf complete

    // ---- Phase 2: 16 subtiles (this wave's half), prefetch-pipelined ----
    const int Tb = half * 16;
    const int rbase = p * 32 + ((g << 3) ^ (((p >> 2) & 3) << 3));
    float aA0=0.f,aA1=0.f,aA2=0.f,aA3=0.f;
    float aB0=0.f,aB1=0.f,aB2=0.f,aB3=0.f;

    f16x4  pjc = *reinterpret_cast<const f16x4*>(pjbuf + rbase + Tb * 512);
    float2 sgc = sigbuf[pair][Tb * 16 + p];

    #pragma unroll 4
    for (int tt = 0; tt < 16; ++tt) {
        const int Tn = Tb + ((tt + 1) & 15);   // wraparound dummy prefetch
        const f16x4  pjn = *reinterpret_cast<const f16x4*>(pjbuf + rbase + Tn * 512);
        const float2 sgn = sigbuf[pair][Tn * 16 + p];

        const f16x4 s4a = pjc + piua;
        const f16x4 b1a = __builtin_elementwise_max(s4a, s4a * slope4);
        const f16x4 s4b = pjc + piub;
        const f16x4 b1b = __builtin_elementwise_max(s4b, s4b * slope4);

        __builtin_amdgcn_s_setprio(1);
        f32x4 d1a = __builtin_amdgcn_mfma_f32_16x16x16f16(w2lo, b1a, c1, 0, 0, 0);
        d1a = __builtin_amdgcn_mfma_f32_16x16x16f16(w2hi, b1a, d1a, 0, 0, 0);
        f32x4 d1b = __builtin_amdgcn_mfma_f32_16x16x16f16(w2lo, b1b, c1, 0, 0, 0);
        d1b = __builtin_amdgcn_mfma_f32_16x16x16f16(w2hi, b1b, d1b, 0, 0, 0);
        __builtin_amdgcn_s_setprio(0);

        const float sa0 = 0.505f * sgc.x, sa1 = 0.495f * sgc.x;
        const float sb0 = 0.505f * sgc.y, sb1 = 0.495f * sgc.y;
        aA0 = fmaf(sa0, d1a[0], fmaf(sa1, fabsf(d1a[0]), aA0));
        aA1 = fmaf(sa0, d1a[1], fmaf(sa1, fabsf(d1a[1]), aA1));
        aA2 = fmaf(sa0, d1a[2], fmaf(sa1, fabsf(d1a[2]), aA2));
        aA3 = fmaf(sa0, d1a[3], fmaf(sa1, fabsf(d1a[3]), aA3));
        aB0 = fmaf(sb0, d1b[0], fmaf(sb1, fabsf(d1b[0]), aB0));
        aB1 = fmaf(sb0, d1b[1], fmaf(sb1, fabsf(d1b[1]), aB1));
        aB2 = fmaf(sb0, d1b[2], fmaf(sb1, fabsf(d1b[2]), aB2));
        aB3 = fmaf(sb0, d1b[3], fmaf(sb1, fabsf(d1b[3]), aB3));

        pjc = pjn; sgc = sgn;
    }

    // ---- Epilogue: dot with w3, fold node / bc3 term, butterfly ----
    float ppa = fmaf(aA0, w3r[0], fmaf(aA1, w3r[1], fmaf(aA2, w3r[2], aA3 * w3r[3])));
    float ppb = fmaf(aB0, w3r[0], fmaf(aB1, w3r[1], fmaf(aB2, w3r[2], aB3 * w3r[3])));
    if (half == 0) {
        ppa += pna;
        ppb += pnb;
    } else {
        ppa = fmaf(bc3[0], vsa, ppa);
        ppb = fmaf(bc3[0], vsb, ppb);
    }

    #pragma unroll
    for (int off = 32; off > 0; off >>= 1) {
        ppa += __shfl_xor(ppa, off, 64);
        ppb += __shfl_xor(ppb, off, 64);
    }

    if (l == 0) sred[wv] = make_float2(ppa, ppb);
    __syncthreads();

    if (half == 0 && l == 0) {
        const float2 r0 = sred[pair];
        const float2 r1 = sred[pair + 4];
        out[ia * 2 + 0] = xia.y;               // out0 = x[...,1]
        out[ia * 2 + 1] = r0.x + r1.x + bn3[0];
        out[ib * 2 + 0] = xib.y;
        out[ib * 2 + 1] = r0.y + r1.y + bn3[0];
    }
}

extern "C" void kernel_launch(void* const* d_in, const int* in_sizes, int n_in,
                              void* d_out, int out_size, void* d_ws, size_t ws_size,
                              hipStream_t stream) {
    const float* x       = (const float*)d_in[0];
    const float* Wn1     = (const float*)d_in[1];
    const float* bn1     = (const float*)d_in[2];
    const float* Wn2     = (const float*)d_in[3];
    const float* bn2     = (const float*)d_in[4];
    const float* Wn3     = (const float*)d_in[5];
    const float* bn3     = (const float*)d_in[6];
    const float* Wc1     = (const float*)d_in[7];
    const float* bc1     = (const float*)d_in[8];
    const float* Wc2     = (const float*)d_in[9];
    const float* bc2     = (const float*)d_in[10];
    const float* Wc3     = (const float*)d_in[11];
    const float* bc3     = (const float*)d_in[12];
    const float* A_param = (const float*)d_in[13];
    float* out = (float*)d_out;

    const int BN = 16 * 512;          // 8192 rows; 8 per block

    fused_split<<<BN / 8, 512, 0, stream>>>(x, Wn1, bn1, Wn2, bn2, Wn3, bn3,
                                            Wc1, bc1, Wc2, bc2, Wc3, bc3,
                                            A_param, out);
}

// Round 14
// 23.737 us; speedup vs baseline: 1.0353x; 1.0353x over previous
//
#include <hip/hip_runtime.h>

#define NEG_SLOPE 0.01f

typedef _Float16 f16;
typedef _Float16 f16x4 __attribute__((ext_vector_type(4)));
typedef _Float16 f16x8 __attribute__((ext_vector_type(8)));
typedef float    f32x4 __attribute__((ext_vector_type(4)));

__device__ __forceinline__ float leaky(float v) {
    return fmaxf(v, NEG_SLOPE * v);
}

// ---------------- Fully fused, 2 rows/wave, paired-b128 LDS ----------------
// 1024 blocks x 256 thr (4 waves). Wave wv owns rows (ia, ia+1), ia = blk*8+wv*2.
// pj LDS layout (pair-b128, conflict-free): ch[4g..4g+3] of j = Tp*32+todd*16+p
//   at byte  Tp*1024 + (p*4+g)*16 + todd*8.
//   Lane (p,g) ds_read_b128 at Tp*1024 + (p*4+g)*16 -> {pj4(T=2Tp), pj4(T=2Tp+1)}.
//   Wave's 64 addrs = {0,16,..,1008}+base: sequential 1KB, all 32 banks uniform.
// sig LDS layout: float2(sa,sb) of j at (j>>5)*256 + (j&15)*16 + ((j>>4)&1)*8;
//   lane reads float4 = both subtiles' pairs (g-broadcast, 2-way free alias).
// Phase 2: 16 pair-iters, prefetch 1 pair ahead (= 2 subtiles ~ covers LDS lat):
//   per subtile per row: b1 = pk_leaky(pj4+piu4); d1 = 2 chained MFMAs (hi/lo);
//   p[e] += sig*d1[e]; q[e] += sig*|d1[e]|  (leaky folded into w3p/w3a epilogue)
__global__ __launch_bounds__(256, 4) void fused_pairb(
    const float* __restrict__ x,
    const float* __restrict__ Wn1, const float* __restrict__ bn1,
    const float* __restrict__ Wn2, const float* __restrict__ bn2,
    const float* __restrict__ Wn3, const float* __restrict__ bn3,
    const float* __restrict__ Wc1, const float* __restrict__ bc1,
    const float* __restrict__ Wc2, const float* __restrict__ bc2,
    const float* __restrict__ Wc3, const float* __restrict__ bc3,
    const float* __restrict__ A_param,
    float* __restrict__ out)
{
    __shared__ unsigned char pjbuf[512 * 32];   // 16 KB, pair-b128 layout
    __shared__ float2 shn[4][64];               // node h1 pairs, per wave
    __shared__ unsigned char sigbuf[4][4096];   // sigmoid pairs, pair layout

    const int t  = threadIdx.x;
    const int l  = t & 63;
    const int wv = t >> 6;
    const int p  = l & 15;            // pair slot within 16-j tile
    const int g  = l >> 4;            // channel group
    const int c4 = g << 2;
    const int ia = blockIdx.x * 8 + wv * 2;   // even global row (b*512 + i0)
    const int ib = ia + 1;
    const int bb = ia >> 9;
    const int i0 = ia & 511, i1 = i0 + 1;

    const float* xb = x + bb * 1024;  // x[b][j][2]

    // ---- Phase 1a: stage pj; thread t covers j = t, t+256 ----
    #pragma unroll
    for (int jj = 0; jj < 2; ++jj) {
        const int j = t + jj * 256;
        const float2 xj = *reinterpret_cast<const float2*>(xb + j * 2);
        f16 v[16];
        #pragma unroll
        for (int c = 0; c < 16; ++c)
            v[c] = (f16)fmaf(xj.x, Wc1[c], xj.y * Wc1[16 + c]);
        const int base = (j >> 5) * 1024 + (j & 15) * 64 + ((j >> 4) & 1) * 8;
        #pragma unroll
        for (int gg = 0; gg < 4; ++gg)
            *reinterpret_cast<f16x4*>(pjbuf + base + gg * 16) =
                (f16x4){v[4*gg], v[4*gg+1], v[4*gg+2], v[4*gg+3]};
    }

    const float2 xia = *reinterpret_cast<const float2*>(xb + i0 * 2);
    const float2 xib = *reinterpret_cast<const float2*>(xb + i1 * 2);

    // ---- Phase 1b: weight fragments (row-independent) + per-row piu ----
    f16x4 w2lo, w2hi, piua, piub;
    f32x4 c1;
    float w3p[4], w3a[4];
    #pragma unroll
    for (int e = 0; e < 4; ++e) {
        const int c = c4 + e;
        const float w2 = Wc2[c * 16 + p];
        const f16 hw = (f16)w2;
        w2hi[e] = hw; w2lo[e] = (f16)(w2 - (float)hw);
        c1[e]  = bc2[c];
        const float w3 = Wc3[c];
        w3p[e] = 0.505f * w3;
        w3a[e] = 0.495f * w3;
        const float wi0 = Wc1[32 + c], wi1 = Wc1[48 + c], bce = bc1[c];
        piua[e] = (f16)fmaf(xia.x, wi0, fmaf(xia.y, wi1, bce));
        piub[e] = (f16)fmaf(xib.x, wi0, fmaf(xib.y, wi1, bce));
    }
    const f16x4 slope4 = {(f16)NEG_SLOPE, (f16)NEG_SLOPE, (f16)NEG_SLOPE, (f16)NEG_SLOPE};

    // ---- Phase 1c: node MLP for both rows (shared Wn2 loads, split chains) ----
    const float h1a = leaky(fmaf(xia.x, Wn1[l], fmaf(xia.y, Wn1[64 + l], bn1[l])));
    const float h1b = leaky(fmaf(xib.x, Wn1[l], fmaf(xib.y, Wn1[64 + l], bn1[l])));
    shn[wv][l] = make_float2(h1a, h1b);
    float na0 = bn2[l], nb0 = 0.f, na1 = 0.f, nb1 = 0.f;
    #pragma unroll 8
    for (int c = 0; c < 64; c += 2) {
        const float w0 = Wn2[c * 64 + l];
        const float w1 = Wn2[(c + 1) * 64 + l];
        const float2 h0 = shn[wv][c];
        const float2 h2 = shn[wv][c + 1];
        na0 = fmaf(h0.x, w0, na0);
        nb0 = fmaf(h0.y, w0, nb0);
        na1 = fmaf(h2.x, w1, na1);
        nb1 = fmaf(h2.y, w1, nb1);
    }
    const float pna = leaky(na0 + na1) * Wn3[l];
    const float pnb = leaky(nb0 + nb1 + bn2[l]) * Wn3[l];

    // ---- Phase 1d: sigmoid rows -> LDS pair layout (intra-wave use) ----
    float vsa = 0.f, vsb = 0.f;
    const float* Ara = A_param + i0 * 512;
    const float* Arb = Ara + 512;
    #pragma unroll
    for (int s = 0; s < 8; ++s) {
        const int j = s * 64 + l;
        float sa = __fdividef(1.f, 1.f + __expf(-Ara[j]));
        float sb = __fdividef(1.f, 1.f + __expf(-Arb[j]));
        if (j == i0) sa = 0.f;        // sigmoid(0 - 1e5) == 0 in f32
        if (j == i1) sb = 0.f;
        vsa += sa; vsb += sb;
        const int sad = (j >> 5) * 256 + (j & 15) * 16 + ((j >> 4) & 1) * 8;
        *reinterpret_cast<float2*>(&sigbuf[wv][sad]) = make_float2(sa, sb);
    }

    __syncthreads();   // pjbuf staging complete (shn/sigbuf are intra-wave)

    // ---- Phase 2: 16 pair-iters (32 subtiles), prefetch 1 pair ahead ----
    const int rb  = p * 64 + g * 16;
    const unsigned char* sgB = sigbuf[wv] + p * 16;

    float pA0=0.f,pA1=0.f,pA2=0.f,pA3=0.f, qA0=0.f,qA1=0.f,qA2=0.f,qA3=0.f;
    float pB0=0.f,pB1=0.f,pB2=0.f,pB3=0.f, qB0=0.f,qB1=0.f,qB2=0.f,qB3=0.f;

    f16x8  pjc = *reinterpret_cast<const f16x8*>(pjbuf + rb);
    float4 sgc = *reinterpret_cast<const float4*>(sgB);

    #pragma unroll 4
    for (int Tp = 0; Tp < 16; ++Tp) {
        const int Tn = (Tp + 1) & 15;  // wraparound dummy prefetch on last iter
        const f16x8  pjn = *reinterpret_cast<const f16x8*>(pjbuf + Tn * 1024 + rb);
        const float4 sgn = *reinterpret_cast<const float4*>(sgB + Tn * 256);

        const f16x4 pjE = __builtin_shufflevector(pjc, pjc, 0, 1, 2, 3);
        const f16x4 pjO = __builtin_shufflevector(pjc, pjc, 4, 5, 6, 7);

        // even subtile (T = 2*Tp): rows a, b
        {
            const f16x4 s4a = pjE + piua;
            const f16x4 b1a = __builtin_elementwise_max(s4a, s4a * slope4);
            const f16x4 s4b = pjE + piub;
            const f16x4 b1b = __builtin_elementwise_max(s4b, s4b * slope4);
            f32x4 d1a = __builtin_amdgcn_mfma_f32_16x16x16f16(w2lo, b1a, c1, 0, 0, 0);
            d1a = __builtin_amdgcn_mfma_f32_16x16x16f16(w2hi, b1a, d1a, 0, 0, 0);
            f32x4 d1b = __builtin_amdgcn_mfma_f32_16x16x16f16(w2lo, b1b, c1, 0, 0, 0);
            d1b = __builtin_amdgcn_mfma_f32_16x16x16f16(w2hi, b1b, d1b, 0, 0, 0);
            const float sa = sgc.x, sb = sgc.y;
            pA0 = fmaf(sa, d1a[0], pA0);  qA0 = fmaf(sa, fabsf(d1a[0]), qA0);
            pA1 = fmaf(sa, d1a[1], pA1);  qA1 = fmaf(sa, fabsf(d1a[1]), qA1);
            pA2 = fmaf(sa, d1a[2], pA2);  qA2 = fmaf(sa, fabsf(d1a[2]), qA2);
            pA3 = fmaf(sa, d1a[3], pA3);  qA3 = fmaf(sa, fabsf(d1a[3]), qA3);
            pB0 = fmaf(sb, d1b[0], pB0);  qB0 = fmaf(sb, fabsf(d1b[0]), qB0);
            pB1 = fmaf(sb, d1b[1], pB1);  qB1 = fmaf(sb, fabsf(d1b[1]), qB1);
            pB2 = fmaf(sb, d1b[2], pB2);  qB2 = fmaf(sb, fabsf(d1b[2]), qB2);
            pB3 = fmaf(sb, d1b[3], pB3);  qB3 = fmaf(sb, fabsf(d1b[3]), qB3);
        }
        // odd subtile (T = 2*Tp+1): rows a, b
        {
            const f16x4 s4a = pjO + piua;
            const f16x4 b1a = __builtin_elementwise_max(s4a, s4a * slope4);
            const f16x4 s4b = pjO + piub;
            const f16x4 b1b = __builtin_elementwise_max(s4b, s4b * slope4);
            f32x4 d1a = __builtin_amdgcn_mfma_f32_16x16x16f16(w2lo, b1a, c1, 0, 0, 0);
            d1a = __builtin_amdgcn_mfma_f32_16x16x16f16(w2hi, b1a, d1a, 0, 0, 0);
            f32x4 d1b = __builtin_amdgcn_mfma_f32_16x16x16f16(w2lo, b1b, c1, 0, 0, 0);
            d1b = __builtin_amdgcn_mfma_f32_16x16x16f16(w2hi, b1b, d1b, 0, 0, 0);
            const float sa = sgc.z, sb = sgc.w;
            pA0 = fmaf(sa, d1a[0], pA0);  qA0 = fmaf(sa, fabsf(d1a[0]), qA0);
            pA1 = fmaf(sa, d1a[1], pA1);  qA1 = fmaf(sa, fabsf(d1a[1]), qA1);
            pA2 = fmaf(sa, d1a[2], pA2);  qA2 = fmaf(sa, fabsf(d1a[2]), qA2);
            pA3 = fmaf(sa, d1a[3], pA3);  qA3 = fmaf(sa, fabsf(d1a[3]), qA3);
            pB0 = fmaf(sb, d1b[0], pB0);  qB0 = fmaf(sb, fabsf(d1b[0]), qB0);
            pB1 = fmaf(sb, d1b[1], pB1);  qB1 = fmaf(sb, fabsf(d1b[1]), qB1);
            pB2 = fmaf(sb, d1b[2], pB2);  qB2 = fmaf(sb, fabsf(d1b[2]), qB2);
            pB3 = fmaf(sb, d1b[3], pB3);  qB3 = fmaf(sb, fabsf(d1b[3]), qB3);
        }

        pjc = pjn; sgc = sgn;
    }

    // ---- Epilogue: leaky fold (w3p/w3a), node + bc3 terms, butterflies ----
    float ppa = pA0*w3p[0] + qA0*w3a[0] + pA1*w3p[1] + qA1*w3a[1]
              + pA2*w3p[2] + qA2*w3a[2] + pA3*w3p[3] + qA3*w3a[3];
    float ppb = pB0*w3p[0] + qB0*w3a[0] + pB1*w3p[1] + qB1*w3a[1]
              + pB2*w3p[2] + qB2*w3a[2] + pB3*w3p[3] + qB3*w3a[3];
    ppa = fmaf(bc3[0], vsa, ppa) + pna;
    ppb = fmaf(bc3[0], vsb, ppb) + pnb;

    #pragma unroll
    for (int off = 32; off > 0; off >>= 1) {
        ppa += __shfl_xor(ppa, off, 64);
        ppb += __shfl_xor(ppb, off, 64);
    }

    if (l == 0) {
        out[ia * 2 + 0] = xia.y;               // out0 = x[...,1]
        out[ia * 2 + 1] = ppa + bn3[0];
        out[ib * 2 + 0] = xib.y;
        out[ib * 2 + 1] = ppb + bn3[0];
    }
}

extern "C" void kernel_launch(void* const* d_in, const int* in_sizes, int n_in,
                              void* d_out, int out_size, void* d_ws, size_t ws_size,
                              hipStream_t stream) {
    const float* x       = (const float*)d_in[0];
    const float* Wn1     = (const float*)d_in[1];
    const float* bn1     = (const float*)d_in[2];
    const float* Wn2     = (const float*)d_in[3];
    const float* bn2     = (const float*)d_in[4];
    const float* Wn3     = (const float*)d_in[5];
    const float* bn3     = (const float*)d_in[6];
    const float* Wc1     = (const float*)d_in[7];
    const float* bc1     = (const float*)d_in[8];
    const float* Wc2     = (const float*)d_in[9];
    const float* bc2     = (const float*)d_in[10];
    const float* Wc3     = (const float*)d_in[11];
    const float* bc3     = (const float*)d_in[12];
    const float* A_param = (const float*)d_in[13];
    float* out = (float*)d_out;

    const int BN = 16 * 512;          // 8192 rows; 8 per block (2 per wave)

    fused_pairb<<<BN / 8, 256, 0, stream>>>(x, Wn1, bn1, Wn2, bn2, Wn3, bn3,
                                            Wc1, bc1, Wc2, bc2, Wc3, bc3,
                                            A_param, out);
}

// Round 15
// 21.810 us; speedup vs baseline: 1.1267x; 1.0883x over previous
//
#include <hip/hip_runtime.h>

#define NEG_SLOPE 0.01f

typedef _Float16 f16;
typedef _Float16 f16x4 __attribute__((ext_vector_type(4)));
typedef float    f32x4 __attribute__((ext_vector_type(4)));

__device__ __forceinline__ float leaky(float v) {
    return fmaxf(v, NEG_SLOPE * v);
}

// ---------------- Fully fused, one kernel, 2 rows per wave ----------------
// (Best-measured configuration: R11, 21.66 us. Clean revert.)
// 1024 blocks x 256 thr. Block covers rows ia = blockIdx*8 .. +7 (same b).
// Wave wv owns rows (ia, ia+1).
// Phase 1: stage pj[512][16] f16 (swizzled) in LDS (shared by all 8 rows);
//          node MLP for both rows (shared Wn2 loads); sigmoid rows -> LDS.
// Phase 2: 32 subtiles, software-pipelined LDS reads (prefetch T+1):
//          one shared pj ds_read feeds BOTH rows' MFMA pairs;
//          accPos[e] += sig*d1[e]; accAbs[e] += sig*|d1[e]|  (abs = free mod)
// Epilogue: leaky folded via w3p=0.505*w3, w3a=0.495*w3; two butterflies.
__global__ __launch_bounds__(256, 4) void fused_all3(
    const float* __restrict__ x,
    const float* __restrict__ Wn1, const float* __restrict__ bn1,
    const float* __restrict__ Wn2, const float* __restrict__ bn2,
    const float* __restrict__ Wn3, const float* __restrict__ bn3,
    const float* __restrict__ Wc1, const float* __restrict__ bc1,
    const float* __restrict__ Wc2, const float* __restrict__ bc2,
    const float* __restrict__ Wc3, const float* __restrict__ bc3,
    const float* __restrict__ A_param,
    float* __restrict__ out)
{
    __shared__ unsigned char pjbuf[512 * 32];   // f16 [512][16], swizzled
    __shared__ float2 shn[4][64];               // node h1 pairs, per wave
    __shared__ float2 sigbuf[4][512];           // sigmoid pairs, per wave

    const int t  = threadIdx.x;
    const int l  = t & 63;
    const int wv = t >> 6;
    const int p  = l & 15;            // pair slot within 16-j tile
    const int g  = l >> 4;            // channel group
    const int c4 = g << 2;
    const int ia = blockIdx.x * 8 + wv * 2;   // even global row (b*512 + i0)
    const int ib = ia + 1;
    const int bb = ia >> 9;
    const int i0 = ia & 511, i1 = i0 + 1;

    const float* xb = x + bb * 1024;  // x[b][j][2]

    // ---- Phase 1a: stage pj (f16) into LDS; thread t covers j = t, t+256 ----
    #pragma unroll
    for (int jj = 0; jj < 2; ++jj) {
        const int j = t + jj * 256;
        const float2 xj = *reinterpret_cast<const float2*>(xb + j * 2);
        f16 v[16];
        #pragma unroll
        for (int c = 0; c < 16; ++c)
            v[c] = (f16)fmaf(xj.x, Wc1[c], xj.y * Wc1[16 + c]);
        const int sw = ((j >> 2) & 3) << 3;
        #pragma unroll
        for (int gg = 0; gg < 4; ++gg) {
            const int addr = j * 32 + ((gg << 3) ^ sw);
            *reinterpret_cast<f16x4*>(pjbuf + addr) =
                (f16x4){v[4*gg], v[4*gg+1], v[4*gg+2], v[4*gg+3]};
        }
    }

    const float2 xia = *reinterpret_cast<const float2*>(xb + i0 * 2);
    const float2 xib = *reinterpret_cast<const float2*>(xb + i1 * 2);

    // ---- Phase 1b: weight fragments (row-independent) + per-row piu ----
    f16x4 w2lo, w2hi, piua, piub;
    f32x4 c1;
    float w3p[4], w3a[4];
    #pragma unroll
    for (int e = 0; e < 4; ++e) {
        const int c = c4 + e;
        const float w2 = Wc2[c * 16 + p];
        const f16 hw = (f16)w2;
        w2hi[e] = hw; w2lo[e] = (f16)(w2 - (float)hw);
        c1[e]  = bc2[c];
        const float w3 = Wc3[c];
        w3p[e] = 0.505f * w3;
        w3a[e] = 0.495f * w3;
        const float wi0 = Wc1[32 + c], wi1 = Wc1[48 + c], bce = bc1[c];
        piua[e] = (f16)fmaf(xia.x, wi0, fmaf(xia.y, wi1, bce));
        piub[e] = (f16)fmaf(xib.x, wi0, fmaf(xib.y, wi1, bce));
    }
    const f16x4 slope4 = {(f16)NEG_SLOPE, (f16)NEG_SLOPE, (f16)NEG_SLOPE, (f16)NEG_SLOPE};

    // ---- Phase 1c: node MLP for both rows (shared Wn2 loads, split chains) ----
    const float h1a = leaky(fmaf(xia.x, Wn1[l], fmaf(xia.y, Wn1[64 + l], bn1[l])));
    const float h1b = leaky(fmaf(xib.x, Wn1[l], fmaf(xib.y, Wn1[64 + l], bn1[l])));
    shn[wv][l] = make_float2(h1a, h1b);
    float na0 = bn2[l], nb0 = 0.f, na1 = 0.f, nb1 = 0.f;
    #pragma unroll 8
    for (int c = 0; c < 64; c += 2) {
        const float w0 = Wn2[c * 64 + l];
        const float w1 = Wn2[(c + 1) * 64 + l];
        const float2 h0 = shn[wv][c];
        const float2 h2 = shn[wv][c + 1];
        na0 = fmaf(h0.x, w0, na0);
        nb0 = fmaf(h0.y, w0, nb0);
        na1 = fmaf(h2.x, w1, na1);
        nb1 = fmaf(h2.y, w1, nb1);
    }
    const float node_a = leaky(na0 + na1) * Wn3[l];
    const float node_b = leaky(nb0 + nb1 + bn2[l]) * Wn3[l];

    // ---- Phase 1d: sigmoid rows for both i's -> LDS (intra-wave use) ----
    float vsa = 0.f, vsb = 0.f;
    const float* Ara = A_param + i0 * 512;
    const float* Arb = Ara + 512;
    #pragma unroll
    for (int s = 0; s < 8; ++s) {
        const int j = s * 64 + l;
        float sa = __fdividef(1.f, 1.f + __expf(-Ara[j]));
        float sb = __fdividef(1.f, 1.f + __expf(-Arb[j]));
        if (j == i0) sa = 0.f;        // sigmoid(0 - 1e5) == 0 in f32
        if (j == i1) sb = 0.f;
        vsa += sa; vsb += sb;
        sigbuf[wv][j] = make_float2(sa, sb);
    }

    __syncthreads();   // pjbuf staging complete (shn/sigbuf are intra-wave)

    // ---- Phase 2: 32 subtiles, prefetch-pipelined, both rows share pj ----
    const int rbase = p * 32 + ((g << 3) ^ (((p >> 2) & 3) << 3));
    float pA0=0.f,pA1=0.f,pA2=0.f,pA3=0.f, qA0=0.f,qA1=0.f,qA2=0.f,qA3=0.f;
    float pB0=0.f,pB1=0.f,pB2=0.f,pB3=0.f, qB0=0.f,qB1=0.f,qB2=0.f,qB3=0.f;

    f16x4  pjc = *reinterpret_cast<const f16x4*>(pjbuf + rbase);
    float2 sgc = sigbuf[wv][p];

    #pragma unroll 4
    for (int T = 0; T < 32; ++T) {
        const int Tn = (T + 1) & 31;   // wraparound dummy prefetch on last iter
        const f16x4  pjn = *reinterpret_cast<const f16x4*>(pjbuf + rbase + Tn * 512);
        const float2 sgn = sigbuf[wv][Tn * 16 + p];

        const f16x4 s4a = pjc + piua;
        const f16x4 b1a = __builtin_elementwise_max(s4a, s4a * slope4);
        const f16x4 s4b = pjc + piub;
        const f16x4 b1b = __builtin_elementwise_max(s4b, s4b * slope4);

        __builtin_amdgcn_s_setprio(1);
        f32x4 d1a = __builtin_amdgcn_mfma_f32_16x16x16f16(w2lo, b1a, c1, 0, 0, 0);
        d1a = __builtin_amdgcn_mfma_f32_16x16x16f16(w2hi, b1a, d1a, 0, 0, 0);
        f32x4 d1b = __builtin_amdgcn_mfma_f32_16x16x16f16(w2lo, b1b, c1, 0, 0, 0);
        d1b = __builtin_amdgcn_mfma_f32_16x16x16f16(w2hi, b1b, d1b, 0, 0, 0);
        __builtin_amdgcn_s_setprio(0);

        const float sa = sgc.x, sb = sgc.y;
        pA0 = fmaf(sa, d1a[0], pA0);  qA0 = fmaf(sa, fabsf(d1a[0]), qA0);
        pA1 = fmaf(sa, d1a[1], pA1);  qA1 = fmaf(sa, fabsf(d1a[1]), qA1);
        pA2 = fmaf(sa, d1a[2], pA2);  qA2 = fmaf(sa, fabsf(d1a[2]), qA2);
        pA3 = fmaf(sa, d1a[3], pA3);  qA3 = fmaf(sa, fabsf(d1a[3]), qA3);
        pB0 = fmaf(sb, d1b[0], pB0);  qB0 = fmaf(sb, fabsf(d1b[0]), qB0);
        pB1 = fmaf(sb, d1b[1], pB1);  qB1 = fmaf(sb, fabsf(d1b[1]), qB1);
        pB2 = fmaf(sb, d1b[2], pB2);  qB2 = fmaf(sb, fabsf(d1b[2]), qB2);
        pB3 = fmaf(sb, d1b[3], pB3);  qB3 = fmaf(sb, fabsf(d1b[3]), qB3);

        pjc = pjn; sgc = sgn;
    }

    // ---- Epilogue: leaky fold (0.505/0.495 in w3p/w3a), node, butterfly ----
    float ppa = pA0*w3p[0] + qA0*w3a[0] + pA1*w3p[1] + qA1*w3a[1]
              + pA2*w3p[2] + qA2*w3a[2] + pA3*w3p[3] + qA3*w3a[3];
    float ppb = pB0*w3p[0] + qB0*w3a[0] + pB1*w3p[1] + qB1*w3a[1]
              + pB2*w3p[2] + qB2*w3a[2] + pB3*w3p[3] + qB3*w3a[3];

    ppa = fmaf(bc3[0], vsa, ppa) + node_a;
    ppb = fmaf(bc3[0], vsb, ppb) + node_b;

    #pragma unroll
    for (int off = 32; off > 0; off >>= 1) {
        ppa += __shfl_xor(ppa, off, 64);
        ppb += __shfl_xor(ppb, off, 64);
    }

    if (l == 0) {
        out[ia * 2 + 0] = xia.y;               // out0 = x[...,1]
        out[ia * 2 + 1] = ppa + bn3[0];
        out[ib * 2 + 0] = xib.y;
        out[ib * 2 + 1] = ppb + bn3[0];
    }
}

extern "C" void kernel_launch(void* const* d_in, const int* in_sizes, int n_in,
                              void* d_out, int out_size, void* d_ws, size_t ws_size,
                              hipStream_t stream) {
    const float* x       = (const float*)d_in[0];
    const float* Wn1     = (const float*)d_in[1];
    const float* bn1     = (const float*)d_in[2];
    const float* Wn2     = (const float*)d_in[3];
    const float* bn2     = (const float*)d_in[4];
    const float* Wn3     = (const float*)d_in[5];
    const float* bn3     = (const float*)d_in[6];
    const float* Wc1     = (const float*)d_in[7];
    const float* bc1     = (const float*)d_in[8];
    const float* Wc2     = (const float*)d_in[9];
    const float* bc2     = (const float*)d_in[10];
    const float* Wc3     = (const float*)d_in[11];
    const float* bc3     = (const float*)d_in[12];
    const float* A_param = (const float*)d_in[13];
    float* out = (float*)d_out;

    const int BN = 16 * 512;          // 8192 rows; 8 per block (2 per wave)

    fused_all3<<<BN / 8, 256, 0, stream>>>(x, Wn1, bn1, Wn2, bn2, Wn3, bn3,
                                           Wc1, bc1, Wc2, bc2, Wc3, bc3,
                                           A_param, out);
}

// Round 16
// 20.510 us; speedup vs baseline: 1.1981x; 1.0633x over previous
//
#include <hip/hip_runtime.h>

#define NEG_SLOPE 0.01f

typedef _Float16 f16;
typedef _Float16 f16x4 __attribute__((ext_vector_type(4)));
typedef float    f32x4 __attribute__((ext_vector_type(4)));

__device__ __forceinline__ float leaky(float v) {
    return fmaxf(v, NEG_SLOPE * v);
}

// ---------------- R11 structure, single-MFMA + depth-2 prefetch ----------------
// 1024 blocks x 256 thr. Wave wv owns rows (ia, ia+1), ia = blockIdx*8 + wv*2.
// Differences vs R11/R15 (otherwise frozen):
//   * w2 as round-to-nearest f16, ONE MFMA per row per subtile (chain halved).
//   * LDS prefetch depth 2 (covers ~120cy ds_read latency vs ~66cy/iter issue).
__global__ __launch_bounds__(256, 4) void fused_final(
    const float* __restrict__ x,
    const float* __restrict__ Wn1, const float* __restrict__ bn1,
    const float* __restrict__ Wn2, const float* __restrict__ bn2,
    const float* __restrict__ Wn3, const float* __restrict__ bn3,
    const float* __restrict__ Wc1, const float* __restrict__ bc1,
    const float* __restrict__ Wc2, const float* __restrict__ bc2,
    const float* __restrict__ Wc3, const float* __restrict__ bc3,
    const float* __restrict__ A_param,
    float* __restrict__ out)
{
    __shared__ unsigned char pjbuf[512 * 32];   // f16 [512][16], swizzled
    __shared__ float2 shn[4][64];               // node h1 pairs, per wave
    __shared__ float2 sigbuf[4][512];           // sigmoid pairs, per wave

    const int t  = threadIdx.x;
    const int l  = t & 63;
    const int wv = t >> 6;
    const int p  = l & 15;            // pair slot within 16-j tile
    const int g  = l >> 4;            // channel group
    const int c4 = g << 2;
    const int ia = blockIdx.x * 8 + wv * 2;   // even global row (b*512 + i0)
    const int ib = ia + 1;
    const int bb = ia >> 9;
    const int i0 = ia & 511, i1 = i0 + 1;

    const float* xb = x + bb * 1024;  // x[b][j][2]

    // ---- Phase 1a: stage pj (f16) into LDS; thread t covers j = t, t+256 ----
    #pragma unroll
    for (int jj = 0; jj < 2; ++jj) {
        const int j = t + jj * 256;
        const float2 xj = *reinterpret_cast<const float2*>(xb + j * 2);
        f16 v[16];
        #pragma unroll
        for (int c = 0; c < 16; ++c)
            v[c] = (f16)fmaf(xj.x, Wc1[c], xj.y * Wc1[16 + c]);
        const int sw = ((j >> 2) & 3) << 3;
        #pragma unroll
        for (int gg = 0; gg < 4; ++gg) {
            const int addr = j * 32 + ((gg << 3) ^ sw);
            *reinterpret_cast<f16x4*>(pjbuf + addr) =
                (f16x4){v[4*gg], v[4*gg+1], v[4*gg+2], v[4*gg+3]};
        }
    }

    const float2 xia = *reinterpret_cast<const float2*>(xb + i0 * 2);
    const float2 xib = *reinterpret_cast<const float2*>(xb + i1 * 2);

    // ---- Phase 1b: weight fragments (row-independent) + per-row piu ----
    f16x4 w2h, piua, piub;
    f32x4 c1;
    float w3p[4], w3a[4];
    #pragma unroll
    for (int e = 0; e < 4; ++e) {
        const int c = c4 + e;
        w2h[e] = (f16)Wc2[c * 16 + p];       // RTN f16 (single-MFMA path)
        c1[e]  = bc2[c];
        const float w3 = Wc3[c];
        w3p[e] = 0.505f * w3;
        w3a[e] = 0.495f * w3;
        const float wi0 = Wc1[32 + c], wi1 = Wc1[48 + c], bce = bc1[c];
        piua[e] = (f16)fmaf(xia.x, wi0, fmaf(xia.y, wi1, bce));
        piub[e] = (f16)fmaf(xib.x, wi0, fmaf(xib.y, wi1, bce));
    }
    const f16x4 slope4 = {(f16)NEG_SLOPE, (f16)NEG_SLOPE, (f16)NEG_SLOPE, (f16)NEG_SLOPE};

    // ---- Phase 1c: node MLP for both rows (shared Wn2 loads, split chains) ----
    const float h1a = leaky(fmaf(xia.x, Wn1[l], fmaf(xia.y, Wn1[64 + l], bn1[l])));
    const float h1b = leaky(fmaf(xib.x, Wn1[l], fmaf(xib.y, Wn1[64 + l], bn1[l])));
    shn[wv][l] = make_float2(h1a, h1b);
    float na0 = bn2[l], nb0 = 0.f, na1 = 0.f, nb1 = 0.f;
    #pragma unroll 8
    for (int c = 0; c < 64; c += 2) {
        const float w0 = Wn2[c * 64 + l];
        const float w1 = Wn2[(c + 1) * 64 + l];
        const float2 h0 = shn[wv][c];
        const float2 h2 = shn[wv][c + 1];
        na0 = fmaf(h0.x, w0, na0);
        nb0 = fmaf(h0.y, w0, nb0);
        na1 = fmaf(h2.x, w1, na1);
        nb1 = fmaf(h2.y, w1, nb1);
    }
    const float node_a = leaky(na0 + na1) * Wn3[l];
    const float node_b = leaky(nb0 + nb1 + bn2[l]) * Wn3[l];

    // ---- Phase 1d: sigmoid rows for both i's -> LDS (intra-wave use) ----
    float vsa = 0.f, vsb = 0.f;
    const float* Ara = A_param + i0 * 512;
    const float* Arb = Ara + 512;
    #pragma unroll
    for (int s = 0; s < 8; ++s) {
        const int j = s * 64 + l;
        float sa = __fdividef(1.f, 1.f + __expf(-Ara[j]));
        float sb = __fdividef(1.f, 1.f + __expf(-Arb[j]));
        if (j == i0) sa = 0.f;        // sigmoid(0 - 1e5) == 0 in f32
        if (j == i1) sb = 0.f;
        vsa += sa; vsb += sb;
        sigbuf[wv][j] = make_float2(sa, sb);
    }

    __syncthreads();   // pjbuf staging complete (shn/sigbuf are intra-wave)

    // ---- Phase 2: 32 subtiles, depth-2 prefetch, both rows share pj ----
    const int rbase = p * 32 + ((g << 3) ^ (((p >> 2) & 3) << 3));
    float pA0=0.f,pA1=0.f,pA2=0.f,pA3=0.f, qA0=0.f,qA1=0.f,qA2=0.f,qA3=0.f;
    float pB0=0.f,pB1=0.f,pB2=0.f,pB3=0.f, qB0=0.f,qB1=0.f,qB2=0.f,qB3=0.f;

    f16x4  pj0 = *reinterpret_cast<const f16x4*>(pjbuf + rbase);
    float2 sg0 = sigbuf[wv][p];
    f16x4  pj1 = *reinterpret_cast<const f16x4*>(pjbuf + rbase + 512);
    float2 sg1 = sigbuf[wv][16 + p];

    #pragma unroll 4
    for (int T = 0; T < 32; ++T) {
        const int Tn = (T + 2) & 31;   // wraparound dummy prefetch on last iters
        const f16x4  pjn = *reinterpret_cast<const f16x4*>(pjbuf + rbase + Tn * 512);
        const float2 sgn = sigbuf[wv][Tn * 16 + p];

        const f16x4 s4a = pj0 + piua;
        const f16x4 b1a = __builtin_elementwise_max(s4a, s4a * slope4);
        const f16x4 s4b = pj0 + piub;
        const f16x4 b1b = __builtin_elementwise_max(s4b, s4b * slope4);

        __builtin_amdgcn_s_setprio(1);
        const f32x4 d1a = __builtin_amdgcn_mfma_f32_16x16x16f16(w2h, b1a, c1, 0, 0, 0);
        const f32x4 d1b = __builtin_amdgcn_mfma_f32_16x16x16f16(w2h, b1b, c1, 0, 0, 0);
        __builtin_amdgcn_s_setprio(0);

        const float sa = sg0.x, sb = sg0.y;
        pA0 = fmaf(sa, d1a[0], pA0);  qA0 = fmaf(sa, fabsf(d1a[0]), qA0);
        pA1 = fmaf(sa, d1a[1], pA1);  qA1 = fmaf(sa, fabsf(d1a[1]), qA1);
        pA2 = fmaf(sa, d1a[2], pA2);  qA2 = fmaf(sa, fabsf(d1a[2]), qA2);
        pA3 = fmaf(sa, d1a[3], pA3);  qA3 = fmaf(sa, fabsf(d1a[3]), qA3);
        pB0 = fmaf(sb, d1b[0], pB0);  qB0 = fmaf(sb, fabsf(d1b[0]), qB0);
        pB1 = fmaf(sb, d1b[1], pB1);  qB1 = fmaf(sb, fabsf(d1b[1]), qB1);
        pB2 = fmaf(sb, d1b[2], pB2);  qB2 = fmaf(sb, fabsf(d1b[2]), qB2);
        pB3 = fmaf(sb, d1b[3], pB3);  qB3 = fmaf(sb, fabsf(d1b[3]), qB3);

        pj0 = pj1; sg0 = sg1;
        pj1 = pjn; sg1 = sgn;
    }

    // ---- Epilogue: leaky fold (0.505/0.495 in w3p/w3a), node, butterfly ----
    float ppa = pA0*w3p[0] + qA0*w3a[0] + pA1*w3p[1] + qA1*w3a[1]
              + pA2*w3p[2] + qA2*w3a[2] + pA3*w3p[3] + qA3*w3a[3];
    float ppb = pB0*w3p[0] + qB0*w3a[0] + pB1*w3p[1] + qB1*w3a[1]
              + pB2*w3p[2] + qB2*w3a[2] + pB3*w3p[3] + qB3*w3a[3];

    ppa = fmaf(bc3[0], vsa, ppa) + node_a;
    ppb = fmaf(bc3[0], vsb, ppb) + node_b;

    #pragma unroll
    for (int off = 32; off > 0; off >>= 1) {
        ppa += __shfl_xor(ppa, off, 64);
        ppb += __shfl_xor(ppb, off, 64);
    }

    if (l == 0) {
        out[ia * 2 + 0] = xia.y;               // out0 = x[...,1]
        out[ia * 2 + 1] = ppa + bn3[0];
        out[ib * 2 + 0] = xib.y;
        out[ib * 2 + 1] = ppb + bn3[0];
    }
}

extern "C" void kernel_launch(void* const* d_in, const int* in_sizes, int n_in,
                              void* d_out, int out_size, void* d_ws, size_t ws_size,
                              hipStream_t stream) {
    const float* x       = (const float*)d_in[0];
    const float* Wn1     = (const float*)d_in[1];
    const float* bn1     = (const float*)d_in[2];
    const float* Wn2     = (const float*)d_in[3];
    const float* bn2     = (const float*)d_in[4];
    const float* Wn3     = (const float*)d_in[5];
    const float* bn3     = (const float*)d_in[6];
    const float* Wc1     = (const float*)d_in[7];
    const float* bc1     = (const float*)d_in[8];
    const float* Wc2     = (const float*)d_in[9];
    const float* bc2     = (const float*)d_in[10];
    const float* Wc3     = (const float*)d_in[11];
    const float* bc3     = (const float*)d_in[12];
    const float* A_param = (const float*)d_in[13];
    float* out = (float*)d_out;

    const int BN = 16 * 512;          // 8192 rows; 8 per block (2 per wave)

    fused_final<<<BN / 8, 256, 0, stream>>>(x, Wn1, bn1, Wn2, bn2, Wn3, bn3,
                                            Wc1, bc1, Wc2, bc2, Wc3, bc3,
                                            A_param, out);
}

// Round 18
// 18.689 us; speedup vs baseline: 1.3149x; 1.0975x over previous
//
#include <hip/hip_runtime.h>

#define NEG_SLOPE 0.01f

typedef _Float16 f16;
typedef _Float16 f16x4 __attribute__((ext_vector_type(4)));
typedef float    f32x4 __attribute__((ext_vector_type(4)));

__device__ __forceinline__ float leaky(float v) {
    return fmaxf(v, NEG_SLOPE * v);
}

// ------- R16 structure + 1-stage MFMA result pipeline (fixed rotation) -------
// 1024 blocks x 256 thr. Wave wv owns rows (ia, ia+1), ia = blockIdx*8 + wv*2.
// Frozen from R16: single RTN-f16 MFMA per row, depth-2 LDS prefetch,
// 2-rows/wave sharing, leaky folded as p/q (0.505/0.495 in epilogue).
// Pipeline: at entry of iter T, pj0 = tile T, pj1 = tile T+1; prefetch T+2;
// accumulate tile T-1's MFMA results while tile T's MFMAs are in flight.
__global__ __launch_bounds__(256, 4) void fused_pipe2(
    const float* __restrict__ x,
    const float* __restrict__ Wn1, const float* __restrict__ bn1,
    const float* __restrict__ Wn2, const float* __restrict__ bn2,
    const float* __restrict__ Wn3, const float* __restrict__ bn3,
    const float* __restrict__ Wc1, const float* __restrict__ bc1,
    const float* __restrict__ Wc2, const float* __restrict__ bc2,
    const float* __restrict__ Wc3, const float* __restrict__ bc3,
    const float* __restrict__ A_param,
    float* __restrict__ out)
{
    __shared__ unsigned char pjbuf[512 * 32];   // f16 [512][16], swizzled
    __shared__ float2 shn[4][64];               // node h1 pairs, per wave
    __shared__ float2 sigbuf[4][512];           // sigmoid pairs, per wave

    const int t  = threadIdx.x;
    const int l  = t & 63;
    const int wv = t >> 6;
    const int p  = l & 15;            // pair slot within 16-j tile
    const int g  = l >> 4;            // channel group
    const int c4 = g << 2;
    const int ia = blockIdx.x * 8 + wv * 2;   // even global row (b*512 + i0)
    const int ib = ia + 1;
    const int bb = ia >> 9;
    const int i0 = ia & 511, i1 = i0 + 1;

    const float* xb = x + bb * 1024;  // x[b][j][2]

    // ---- Phase 1a: stage pj (f16) into LDS; thread t covers j = t, t+256 ----
    #pragma unroll
    for (int jj = 0; jj < 2; ++jj) {
        const int j = t + jj * 256;
        const float2 xj = *reinterpret_cast<const float2*>(xb + j * 2);
        f16 v[16];
        #pragma unroll
        for (int c = 0; c < 16; ++c)
            v[c] = (f16)fmaf(xj.x, Wc1[c], xj.y * Wc1[16 + c]);
        const int sw = ((j >> 2) & 3) << 3;
        #pragma unroll
        for (int gg = 0; gg < 4; ++gg) {
            const int addr = j * 32 + ((gg << 3) ^ sw);
            *reinterpret_cast<f16x4*>(pjbuf + addr) =
                (f16x4){v[4*gg], v[4*gg+1], v[4*gg+2], v[4*gg+3]};
        }
    }

    const float2 xia = *reinterpret_cast<const float2*>(xb + i0 * 2);
    const float2 xib = *reinterpret_cast<const float2*>(xb + i1 * 2);

    // ---- Phase 1b: weight fragments (row-independent) + per-row piu ----
    f16x4 w2h, piua, piub;
    f32x4 c1;
    float w3p[4], w3a[4];
    #pragma unroll
    for (int e = 0; e < 4; ++e) {
        const int c = c4 + e;
        w2h[e] = (f16)Wc2[c * 16 + p];       // RTN f16 (single-MFMA path)
        c1[e]  = bc2[c];
        const float w3 = Wc3[c];
        w3p[e] = 0.505f * w3;
        w3a[e] = 0.495f * w3;
        const float wi0 = Wc1[32 + c], wi1 = Wc1[48 + c], bce = bc1[c];
        piua[e] = (f16)fmaf(xia.x, wi0, fmaf(xia.y, wi1, bce));
        piub[e] = (f16)fmaf(xib.x, wi0, fmaf(xib.y, wi1, bce));
    }
    const f16x4 slope4 = {(f16)NEG_SLOPE, (f16)NEG_SLOPE, (f16)NEG_SLOPE, (f16)NEG_SLOPE};

    // ---- Phase 1c: node MLP for both rows (shared Wn2 loads, split chains) ----
    const float h1a = leaky(fmaf(xia.x, Wn1[l], fmaf(xia.y, Wn1[64 + l], bn1[l])));
    const float h1b = leaky(fmaf(xib.x, Wn1[l], fmaf(xib.y, Wn1[64 + l], bn1[l])));
    shn[wv][l] = make_float2(h1a, h1b);
    float na0 = bn2[l], nb0 = 0.f, na1 = 0.f, nb1 = 0.f;
    #pragma unroll 8
    for (int c = 0; c < 64; c += 2) {
        const float w0 = Wn2[c * 64 + l];
        const float w1 = Wn2[(c + 1) * 64 + l];
        const float2 h0 = shn[wv][c];
        const float2 h2 = shn[wv][c + 1];
        na0 = fmaf(h0.x, w0, na0);
        nb0 = fmaf(h0.y, w0, nb0);
        na1 = fmaf(h2.x, w1, na1);
        nb1 = fmaf(h2.y, w1, nb1);
    }
    const float node_a = leaky(na0 + na1) * Wn3[l];
    const float node_b = leaky(nb0 + nb1 + bn2[l]) * Wn3[l];

    // ---- Phase 1d: sigmoid rows for both i's -> LDS (intra-wave use) ----
    float vsa = 0.f, vsb = 0.f;
    const float* Ara = A_param + i0 * 512;
    const float* Arb = Ara + 512;
    #pragma unroll
    for (int s = 0; s < 8; ++s) {
        const int j = s * 64 + l;
        float sa = __fdividef(1.f, 1.f + __expf(-Ara[j]));
        float sb = __fdividef(1.f, 1.f + __expf(-Arb[j]));
        if (j == i0) sa = 0.f;        // sigmoid(0 - 1e5) == 0 in f32
        if (j == i1) sb = 0.f;
        vsa += sa; vsb += sb;
        sigbuf[wv][j] = make_float2(sa, sb);
    }

    __syncthreads();   // pjbuf staging complete (shn/sigbuf are intra-wave)

    // ---- Phase 2: 32 subtiles; depth-2 LDS prefetch; 1-stage result pipe ----
    const int rbase = p * 32 + ((g << 3) ^ (((p >> 2) & 3) << 3));
    float pA0=0.f,pA1=0.f,pA2=0.f,pA3=0.f, qA0=0.f,qA1=0.f,qA2=0.f,qA3=0.f;
    float pB0=0.f,pB1=0.f,pB2=0.f,pB3=0.f, qB0=0.f,qB1=0.f,qB2=0.f,qB3=0.f;

    f16x4  pj0 = *reinterpret_cast<const f16x4*>(pjbuf + rbase);            // tile 0
    float2 sg0 = sigbuf[wv][p];
    f16x4  pj1 = *reinterpret_cast<const f16x4*>(pjbuf + rbase + 512);      // tile 1
    float2 sg1 = sigbuf[wv][16 + p];

    // prologue: issue tile 0's MFMAs; refill pj1 with tile 2 (correct fill!)
    f16x4 s4a = pj0 + piua;
    f16x4 b1a = __builtin_elementwise_max(s4a, s4a * slope4);
    f16x4 s4b = pj0 + piub;
    f16x4 b1b = __builtin_elementwise_max(s4b, s4b * slope4);
    f32x4 dpa = __builtin_amdgcn_mfma_f32_16x16x16f16(w2h, b1a, c1, 0, 0, 0);
    f32x4 dpb = __builtin_amdgcn_mfma_f32_16x16x16f16(w2h, b1b, c1, 0, 0, 0);
    float spa = sg0.x, spb = sg0.y;                                         // tile 0 sig
    pj0 = pj1; sg0 = sg1;                                                   // -> tile 1
    pj1 = *reinterpret_cast<const f16x4*>(pjbuf + rbase + 2 * 512);         // tile 2
    sg1 = sigbuf[wv][2 * 16 + p];

    #pragma unroll 4
    for (int T = 1; T < 32; ++T) {
        // prefetch tile T+2 (wraps to dummy on last two iters)
        const int Tn = (T + 2) & 31;
        const f16x4  pjn = *reinterpret_cast<const f16x4*>(pjbuf + rbase + Tn * 512);
        const float2 sgn = sigbuf[wv][Tn * 16 + p];

        // issue tile T's MFMAs
        s4a = pj0 + piua;
        b1a = __builtin_elementwise_max(s4a, s4a * slope4);
        s4b = pj0 + piub;
        b1b = __builtin_elementwise_max(s4b, s4b * slope4);
        const f32x4 dca = __builtin_amdgcn_mfma_f32_16x16x16f16(w2h, b1a, c1, 0, 0, 0);
        const f32x4 dcb = __builtin_amdgcn_mfma_f32_16x16x16f16(w2h, b1b, c1, 0, 0, 0);

        // accumulate tile T-1's results (overlaps the MFMAs above)
        pA0 = fmaf(spa, dpa[0], pA0);  qA0 = fmaf(spa, fabsf(dpa[0]), qA0);
        pA1 = fmaf(spa, dpa[1], pA1);  qA1 = fmaf(spa, fabsf(dpa[1]), qA1);
        pA2 = fmaf(spa, dpa[2], pA2);  qA2 = fmaf(spa, fabsf(dpa[2]), qA2);
        pA3 = fmaf(spa, dpa[3], pA3);  qA3 = fmaf(spa, fabsf(dpa[3]), qA3);
        pB0 = fmaf(spb, dpb[0], pB0);  qB0 = fmaf(spb, fabsf(dpb[0]), qB0);
        pB1 = fmaf(spb, dpb[1], pB1);  qB1 = fmaf(spb, fabsf(dpb[1]), qB1);
        pB2 = fmaf(spb, dpb[2], pB2);  qB2 = fmaf(spb, fabsf(dpb[2]), qB2);
        pB3 = fmaf(spb, dpb[3], pB3);  qB3 = fmaf(spb, fabsf(dpb[3]), qB3);

        // rotate: results, sig, and LDS pipeline
        dpa = dca; dpb = dcb;
        spa = sg0.x; spb = sg0.y;     // tile T's sig
        pj0 = pj1; sg0 = sg1;         // -> tile T+1
        pj1 = pjn; sg1 = sgn;         // -> tile T+2
    }

    // epilogue: accumulate tile 31's results
    pA0 = fmaf(spa, dpa[0], pA0);  qA0 = fmaf(spa, fabsf(dpa[0]), qA0);
    pA1 = fmaf(spa, dpa[1], pA1);  qA1 = fmaf(spa, fabsf(dpa[1]), qA1);
    pA2 = fmaf(spa, dpa[2], pA2);  qA2 = fmaf(spa, fabsf(dpa[2]), qA2);
    pA3 = fmaf(spa, dpa[3], pA3);  qA3 = fmaf(spa, fabsf(dpa[3]), qA3);
    pB0 = fmaf(spb, dpb[0], pB0);  qB0 = fmaf(spb, fabsf(dpb[0]), qB0);
    pB1 = fmaf(spb, dpb[1], pB1);  qB1 = fmaf(spb, fabsf(dpb[1]), qB1);
    pB2 = fmaf(spb, dpb[2], pB2);  qB2 = fmaf(spb, fabsf(dpb[2]), qB2);
    pB3 = fmaf(spb, dpb[3], pB3);  qB3 = fmaf(spb, fabsf(dpb[3]), qB3);

    // ---- Epilogue: leaky fold (0.505/0.495 in w3p/w3a), node, butterfly ----
    float ppa = pA0*w3p[0] + qA0*w3a[0] + pA1*w3p[1] + qA1*w3a[1]
              + pA2*w3p[2] + qA2*w3a[2] + pA3*w3p[3] + qA3*w3a[3];
    float ppb = pB0*w3p[0] + qB0*w3a[0] + pB1*w3p[1] + qB1*w3a[1]
              + pB2*w3p[2] + qB2*w3a[2] + pB3*w3p[3] + qB3*w3a[3];

    ppa = fmaf(bc3[0], vsa, ppa) + node_a;
    ppb = fmaf(bc3[0], vsb, ppb) + node_b;

    #pragma unroll
    for (int off = 32; off > 0; off >>= 1) {
        ppa += __shfl_xor(ppa, off, 64);
        ppb += __shfl_xor(ppb, off, 64);
    }

    if (l == 0) {
        out[ia * 2 + 0] = xia.y;               // out0 = x[...,1]
        out[ia * 2 + 1] = ppa + bn3[0];
        out[ib * 2 + 0] = xib.y;
        out[ib * 2 + 1] = ppb + bn3[0];
    }
}

extern "C" void kernel_launch(void* const* d_in, const int* in_sizes, int n_in,
                              void* d_out, int out_size, void* d_ws, size_t ws_size,
                              hipStream_t stream) {
    const float* x       = (const float*)d_in[0];
    const float* Wn1     = (const float*)d_in[1];
    const float* bn1     = (const float*)d_in[2];
    const float* Wn2     = (const float*)d_in[3];
    const float* bn2     = (const float*)d_in[4];
    const float* Wn3     = (const float*)d_in[5];
    const float* bn3     = (const float*)d_in[6];
    const float* Wc1     = (const float*)d_in[7];
    const float* bc1     = (const float*)d_in[8];
    const float* Wc2     = (const float*)d_in[9];
    const float* bc2     = (const float*)d_in[10];
    const float* Wc3     = (const float*)d_in[11];
    const float* bc3     = (const float*)d_in[12];
    const float* A_param = (const float*)d_in[13];
    float* out = (float*)d_out;

    const int BN = 16 * 512;          // 8192 rows; 8 per block (2 per wave)

    fused_pipe2<<<BN / 8, 256, 0, stream>>>(x, Wn1, bn1, Wn2, bn2, Wn3, bn3,
                                            Wc1, bc1, Wc2, bc2, Wc3, bc3,
                                            A_param, out);
}